// Round 12
// baseline (801.342 us; speedup 1.0000x reference)
//
#include <hip/hip_runtime.h>
#include <hip/hip_bf16.h>

typedef unsigned short u16;
typedef unsigned int u32;
typedef __attribute__((ext_vector_type(8))) u16 u16x8;
typedef __attribute__((ext_vector_type(4))) u16 u16x4;
typedef __attribute__((ext_vector_type(8))) short bf16x8;
typedef __attribute__((ext_vector_type(4))) float f32x4;

__device__ __forceinline__ u16 f2bf(float f) {
  u32 u = __float_as_uint(f);
  u += 0x7fffu + ((u >> 16) & 1u);
  return (u16)(u >> 16);
}
__device__ __forceinline__ float bf2f(u16 h) {
  return __uint_as_float(((u32)h) << 16);
}
__device__ __forceinline__ u16 cvt_bf(float f) {
  __hip_bfloat16 h(f);
  return __builtin_bit_cast(u16, h);
}
__device__ __forceinline__ bf16x8 ld_bf8(const u16* p) {
  return __builtin_bit_cast(bf16x8, *(const u16x8*)p);
}

#if __has_builtin(__builtin_amdgcn_exp2f)
#define EXP2(x) __builtin_amdgcn_exp2f(x)
#else
#define EXP2(x) exp2f(x)
#endif

typedef const void __attribute__((address_space(1)))* gas_t;
typedef void __attribute__((address_space(3)))* las_t;
#define GLOAD_LDS16(gp, lp) __builtin_amdgcn_global_load_lds((gas_t)(gp), (las_t)(lp), 16, 0, 0)

#define QSCALE 0.25503486f       // (1/sqrt(32)) * log2(e), folded into wq q-columns
#define BIAS_MUL 23.08312065f    // 16 * log2(e)

// ---------------- fused head: LN1 (blocks [0,2048)) + weight prep + CPB (blocks [2048,13249)) ----------------
// Each block takes exactly one uniform branch; prep overlaps ln1 instead of serializing before it.
__global__ __launch_bounds__(256, 4) void head_kernel(
    const float* __restrict__ x, const float* __restrict__ n1w, const float* __restrict__ n1b,
    u16* __restrict__ hbuf, u16* __restrict__ xwbuf,
    const float* __restrict__ qkv_w, const float* __restrict__ proj_w,
    const float* __restrict__ fc1_w, const float* __restrict__ fc2_w,
    const float* __restrict__ rt, const float* __restrict__ cw1,
    const float* __restrict__ cb1, const float* __restrict__ cw2,
    u16* __restrict__ wq, u16* __restrict__ wp, u16* __restrict__ w1,
    u16* __restrict__ w2, float* __restrict__ tab2) {
  __shared__ u16 tile[512 * 33];
  __shared__ float red[2][8][32];
  __shared__ float meanv[32], rstdv[32];
  int blk = blockIdx.x, t = threadIdx.x;
  if (blk < 2048) {
    // ---- LN1: 32 pixels per block (R8-proven) ----
    int bi = blk;
    int bimg = bi >> 7, rest = bi & 127, hrow = rest >> 1, half = rest & 1;
    int p = t & 31, g = t >> 5;
    const float* xr = x + (size_t)bimg * 512 * 4096 + (size_t)hrow * 64 + half * 32;
    float s = 0.f, s2 = 0.f;
    for (int i = 0; i < 64; ++i) {
      int c = g * 64 + i;
      float v = xr[(size_t)c * 4096 + p];
      tile[c * 33 + p] = f2bf(v);
      s += v; s2 += v * v;
    }
    red[0][g][p] = s; red[1][g][p] = s2;
    __syncthreads();
    if (t < 32) {
      float ss = 0.f, qq = 0.f;
      for (int gg = 0; gg < 8; ++gg) { ss += red[0][gg][t]; qq += red[1][gg][t]; }
      float mu = ss * (1.f / 512.f);
      float var = qq * (1.f / 512.f) - mu * mu;
      meanv[t] = mu;
      rstdv[t] = rsqrtf(var + 1e-5f);
    }
    __syncthreads();
    int c0 = t * 2;
    float w0 = n1w[c0], w1v = n1w[c0 + 1], b0 = n1b[c0], b1v = n1b[c0 + 1];
    int hy = hrow >> 4, iy = hrow & 15;
    for (int pp = 0; pp < 32; ++pp) {
      int pixel = half * 32 + pp;
      int wx = pixel >> 4, ix = pixel & 15;
      int widx = bimg * 16 + hy * 4 + wx;
      size_t basep = ((size_t)widx * 256 + iy * 16 + ix) * 512;
      u16 rb0 = tile[c0 * 33 + pp], rb1 = tile[(c0 + 1) * 33 + pp];
      float mu = meanv[pp], rs = rstdv[pp];
      float v0 = bf2f(rb0), v1 = bf2f(rb1);
      *(u32*)(xwbuf + basep + c0) = (u32)rb0 | ((u32)rb1 << 16);
      u16 h0 = f2bf((v0 - mu) * rs * w0 + b0);
      u16 h1 = f2bf((v1 - mu) * rs * w1v + b1v);
      *(u32*)(hbuf + basep + c0) = (u32)h0 | ((u32)h1 << 16);
    }
    return;
  }
  int b = blk - 2048;
  if (b < 3072) {
    int idx = b * 256 + t;  // qkv transpose, q cols pre-scaled
    int n = idx >> 9, k = idx & 511;
    float s = n < 512 ? QSCALE : 1.f;
    wq[idx] = f2bf(qkv_w[(size_t)k * 1536 + n] * s);
  } else if (b < 4096) {
    int idx = (b - 3072) * 256 + t;
    int n = idx >> 9, k = idx & 511;
    wp[idx] = f2bf(proj_w[(size_t)k * 512 + n]);
  } else if (b < 8192) {
    int idx = (b - 4096) * 256 + t;  // fc1 permuted
    int n = idx >> 9, k = idx & 511;
    int i = ((n >> 5) << 4) | (n & 15);
    int gsel = (n >> 4) & 1;
    w1[idx] = f2bf(fc1_w[(size_t)k * 2048 + i + gsel * 1024]);
  } else if (b < 10240) {
    int idx = (b - 8192) * 256 + t;  // fc2: N=512, K=1024
    int n = idx >> 10, k = idx & 1023;
    w2[idx] = f2bf(fc2_w[(size_t)k * 512 + n]);
  } else {
    // CPB MLP; alias ln1's shared arrays
    float* hid = (float*)tile;                       // 512 f32
    float (*part)[17] = (float (*)[17])(tile + 4096);  // 16x17 f32
    int tix = b - 10240;  // 0..960
    float r0 = rt[tix * 2], r1 = rt[tix * 2 + 1];
    for (int j = t; j < 512; j += 256) {
      float v = r0 * cw1[j] + r1 * cw1[512 + j] + cb1[j];
      hid[j] = v > 0.f ? v : 0.f;
    }
    __syncthreads();
    int hh = t & 15, seg = t >> 4;
    float acc = 0.f;
    for (int j = seg * 32; j < seg * 32 + 32; ++j) acc += hid[j] * cw2[j * 16 + hh];
    part[seg][hh] = acc;
    __syncthreads();
    if (t < 16) {
      float s = 0.f;
      for (int g = 0; g < 16; ++g) s += part[g][t];
      tab2[t * 961 + tix] = BIAS_MUL / (1.f + __expf(-s)) - 23.0f;
    }
  }
}

// ---------------- 128x128 bf16 MFMA GEMM (R5/R8 proven), XCD-panel mapping ----------------
// EPI: 0 plain bf16 [row][N], 1 out = acc + res(bf16), 3 fused SwiGLU (permuted w1),
//      4 fused final: out_f32(CHW) = acc + res(bf16 token-major) + x(f32 CHW)
template <int EPI>
__global__ __launch_bounds__(256, 4) void gemm_bt(
    const u16* __restrict__ A, const u16* __restrict__ Bt,
    u16* __restrict__ out, const u16* __restrict__ res,
    const float* __restrict__ xg, float* __restrict__ outf,
    int M, int N, int K) {
  __shared__ u16 As[128 * 64];
  __shared__ u16 Bs[128 * 64];
  const int t = threadIdx.x, l = t & 63, wv = t >> 6;
  const int nbx = N >> 7;
  const int wg = (int)blockIdx.x;
  const int xcd = wg & 7, c = wg >> 3;
  const int cm = c / nbx;
  const int m0 = (xcd * 64 + cm) * 128, n0 = (c - cm * nbx) * 128;
  const int wr = wv >> 1, wc = wv & 1;
  const int lr = l & 15, lk = l >> 4;
  f32x4 acc[4][4] = {};
  for (int kt = 0; kt < K; kt += 64) {
#pragma unroll
    for (int j = 0; j < 4; ++j) {
      int qi = j * 256 + t;
      int r = qi >> 3, c8 = (qi & 7) * 8;
      GLOAD_LDS16(A + (size_t)(m0 + r) * K + kt + c8, As + (size_t)(j * 256 + wv * 64) * 8);
    }
#pragma unroll
    for (int j = 0; j < 4; ++j) {
      int qi = j * 256 + t;
      int r = qi >> 3, c8 = (qi & 7) * 8;
      GLOAD_LDS16(Bt + (size_t)(n0 + r) * K + kt + c8, Bs + (size_t)(j * 256 + wv * 64) * 8);
    }
    __syncthreads();
#pragma unroll
    for (int ks = 0; ks < 2; ++ks) {
      bf16x8 a[4], bb[4];
#pragma unroll
      for (int mf = 0; mf < 4; ++mf)
        a[mf] = ld_bf8(As + (wr * 64 + mf * 16 + lr) * 64 + ks * 32 + lk * 8);
#pragma unroll
      for (int nf = 0; nf < 4; ++nf)
        bb[nf] = ld_bf8(Bs + (wc * 64 + nf * 16 + lr) * 64 + ks * 32 + lk * 8);
#pragma unroll
      for (int mf = 0; mf < 4; ++mf)
#pragma unroll
        for (int nf = 0; nf < 4; ++nf)
          acc[mf][nf] = __builtin_amdgcn_mfma_f32_16x16x32_bf16(a[mf], bb[nf], acc[mf][nf], 0, 0, 0);
    }
    __syncthreads();
  }
#pragma unroll
  for (int mf = 0; mf < 4; ++mf) {
    int rbase = m0 + wr * 64 + mf * 16 + lk * 4;
    if constexpr (EPI == 3) {
#pragma unroll
      for (int nf = 0; nf < 4; nf += 2) {
        int colv = n0 + wc * 64 + nf * 16 + lr;
        int i = ((colv >> 5) << 4) | (colv & 15);
#pragma unroll
        for (int jj = 0; jj < 4; ++jj) {
          int row = rbase + jj;
          float val = acc[mf][nf][jj], gate = acc[mf][nf + 1][jj];
          float sil = gate / (1.f + __expf(-gate));
          out[(size_t)row * 1024 + i] = f2bf(sil * val);
        }
      }
    } else if constexpr (EPI == 4) {
      int widx = rbase >> 8, iy = (rbase >> 4) & 15, ix0 = rbase & 15;
      int bimg = widx >> 4, hy = (widx >> 2) & 3, wx = widx & 3;
#pragma unroll
      for (int nf = 0; nf < 4; ++nf) {
        int col = n0 + wc * 64 + nf * 16 + lr;
        size_t obase = (((size_t)(bimg * 512 + col) * 64) + hy * 16 + iy) * 64 + wx * 16 + ix0;
        const float* xp = xg + obase;
        float* op = outf + obase;
#pragma unroll
        for (int jj = 0; jj < 4; ++jj)
          op[jj] = acc[mf][nf][jj] + bf2f(res[(size_t)(rbase + jj) * 512 + col]) + xp[jj];
      }
    } else if constexpr (EPI == 1) {
#pragma unroll
      for (int nf = 0; nf < 4; ++nf) {
        int col = n0 + wc * 64 + nf * 16 + lr;
#pragma unroll
        for (int jj = 0; jj < 4; ++jj) {
          int row = rbase + jj;
          out[(size_t)row * N + col] = f2bf(acc[mf][nf][jj] + bf2f(res[(size_t)row * N + col]));
        }
      }
    } else {
#pragma unroll
      for (int nf = 0; nf < 4; ++nf) {
        int col = n0 + wc * 64 + nf * 16 + lr;
#pragma unroll
        for (int jj = 0; jj < 4; ++jj)
          out[(size_t)(rbase + jj) * N + col] = f2bf(acc[mf][nf][jj]);
      }
    }
  }
}

// ---------------- windowed flash attention: vt double-buffer, single barrier/tile, T14 V-split ----------------
__global__ __launch_bounds__(256, 4) void attn_kernel(
    const u16* __restrict__ qkv, const float* __restrict__ tab2, u16* __restrict__ ob) {
  __shared__ u16 vt[2][32 * 72];        // double-buffered V^T tile (9 KB)
  __shared__ float tabh4[31 * 32 * 4];  // bias table, 4x shifted replicas (15.5 KB)
  __shared__ u16 pl[4][16 * 76];        // per-wave per-mf P tile (9.5 KB)
  const int h = blockIdx.x, w = blockIdx.y;
  const int t = threadIdx.x, l = t & 63, wid = t >> 6;
  const u16* qg = qkv + (size_t)(w * 256) * 1536 + h * 32;
  const u16* kg = qg + 512;
  const u16* vg = qg + 1024;
  const float* th = tab2 + h * 961;
  const int vr = t & 63, vj = t >> 6;
  {  // stage vt[0] (ct = 0)
    u16x8 dv0 = *(const u16x8*)(vg + (size_t)vr * 1536 + vj * 8);
#pragma unroll
    for (int e = 0; e < 8; ++e) vt[0][(vj * 8 + e) * 72 + vr] = dv0[e];
  }
  for (int i = t; i < 992; i += 256) {
    int dy = i >> 5, dx = i & 31;
#pragma unroll
    for (int r = 0; r < 4; ++r) {
      int dxr = dx + r;
      tabh4[i * 4 + r] = (dxr <= 30) ? th[dy * 31 + dxr] : 0.f;
    }
  }
  const int q4 = l >> 4, c0 = l & 15;
  const int dx0 = q4 * 4 - c0 + 15;
  bf16x8 qa[4];
#pragma unroll
  for (int mf = 0; mf < 4; ++mf)
    qa[mf] = ld_bf8(qg + (size_t)(wid * 64 + mf * 16 + c0) * 1536 + q4 * 8);
  f32x4 oacc[4][2] = {};
  float psum[4][4] = {};
  for (int ct = 0; ct < 4; ++ct) {
    __syncthreads();  // vt[ct&1] fully written (prologue or previous iteration)
    bf16x8 bfr[4];
#pragma unroll
    for (int nf = 0; nf < 4; ++nf)
      bfr[nf] = ld_bf8(kg + (size_t)(ct * 64 + nf * 16 + c0) * 1536 + q4 * 8);
    const u16* vcur = vt[ct & 1];
    bf16x8 vfr[2][2];
#pragma unroll
    for (int df = 0; df < 2; ++df)
#pragma unroll
      for (int ks2 = 0; ks2 < 2; ++ks2)
        vfr[df][ks2] = ld_bf8(vcur + (df * 16 + c0) * 72 + ks2 * 32 + q4 * 8);
    // T14 split: issue next V-tile load now; its latency hides under the compute below
    u16x8 dv = {};
    if (ct < 3) dv = *(const u16x8*)(vg + (size_t)((ct + 1) * 64 + vr) * 1536 + vj * 8);
#pragma unroll
    for (int mf = 0; mf < 4; ++mf) {
      const int dyb = wid * 4 + mf - ct * 4 + 15;
      f32x4 sacc[4];
#pragma unroll
      for (int nf = 0; nf < 4; ++nf)
        sacc[nf] = *(const f32x4*)&tabh4[((dyb - nf) * 32 + dx0) * 4];
      __builtin_amdgcn_s_setprio(1);
#pragma unroll
      for (int nf = 0; nf < 4; ++nf)
        sacc[nf] = __builtin_amdgcn_mfma_f32_16x16x32_bf16(qa[mf], bfr[nf], sacc[nf], 0, 0, 0);
      __builtin_amdgcn_s_setprio(0);
#pragma unroll
      for (int nf = 0; nf < 4; ++nf) {
#pragma unroll
        for (int jj = 0; jj < 4; ++jj) {
          float p = EXP2(sacc[nf][jj]);
          psum[mf][jj] += p;
          pl[wid][(q4 * 4 + jj) * 76 + nf * 16 + c0] = cvt_bf(p);
        }
      }
      __builtin_amdgcn_s_setprio(1);
#pragma unroll
      for (int ks2 = 0; ks2 < 2; ++ks2) {
        bf16x8 pa = ld_bf8(&pl[wid][c0 * 76 + ks2 * 32 + q4 * 8]);
        oacc[mf][0] = __builtin_amdgcn_mfma_f32_16x16x32_bf16(pa, vfr[0][ks2], oacc[mf][0], 0, 0, 0);
        oacc[mf][1] = __builtin_amdgcn_mfma_f32_16x16x32_bf16(pa, vfr[1][ks2], oacc[mf][1], 0, 0, 0);
      }
      __builtin_amdgcn_s_setprio(0);
    }
    // deferred write of the prefetched V tile into the other buffer (disjoint from vt[ct&1])
    if (ct < 3) {
#pragma unroll
      for (int e = 0; e < 8; ++e) vt[(ct + 1) & 1][(vj * 8 + e) * 72 + vr] = dv[e];
    }
  }
#pragma unroll
  for (int mf = 0; mf < 4; ++mf) {
#pragma unroll
    for (int jj = 0; jj < 4; ++jj) {
      float s = psum[mf][jj];
      s += __shfl_xor(s, 1);
      s += __shfl_xor(s, 2);
      s += __shfl_xor(s, 4);
      s += __shfl_xor(s, 8);
      float inv = 1.f / s;
      int row = wid * 64 + mf * 16 + q4 * 4 + jj;
      size_t obase = ((size_t)w * 256 + row) * 512 + h * 32;
      ob[obase + c0] = f2bf(oacc[mf][0][jj] * inv);
      ob[obase + 16 + c0] = f2bf(oacc[mf][1][jj] * inv);
    }
  }
}

// ---------------- LN2 ----------------
__global__ __launch_bounds__(256, 4) void ln2_kernel(const u16* __restrict__ r1,
    const float* __restrict__ w, const float* __restrict__ b, u16* __restrict__ h2) {
  int t = threadIdx.x, l = t & 63, wid = t >> 6;
  size_t token = (size_t)blockIdx.x * 4 + wid;
  const u16* rp = r1 + token * 512 + l * 8;
  u16x8 raw = *(const u16x8*)rp;
  float v[8]; float s = 0.f, s2 = 0.f;
#pragma unroll
  for (int i = 0; i < 8; ++i) { v[i] = bf2f(raw[i]); s += v[i]; s2 += v[i] * v[i]; }
#pragma unroll
  for (int m = 1; m < 64; m <<= 1) { s += __shfl_xor(s, m); s2 += __shfl_xor(s2, m); }
  float mu = s * (1.f / 512.f);
  float var = s2 * (1.f / 512.f) - mu * mu;
  float rs = rsqrtf(var + 1e-5f);
  u16x8 o;
#pragma unroll
  for (int i = 0; i < 8; ++i) {
    int c = l * 8 + i;
    o[i] = f2bf((v[i] - mu) * rs * w[c] + b[c]);
  }
  *(u16x8*)(h2 + token * 512 + l * 8) = o;
}

extern "C" void kernel_launch(void* const* d_in, const int* in_sizes, int n_in,
                              void* d_out, int out_size, void* d_ws, size_t ws_size,
                              hipStream_t stream) {
  (void)in_sizes; (void)n_in; (void)out_size; (void)ws_size;
  const float* x = (const float*)d_in[0];
  const float* rel_table = (const float*)d_in[1];
  const float* n1w = (const float*)d_in[2];
  const float* n1b = (const float*)d_in[3];
  const float* n2w = (const float*)d_in[4];
  const float* n2b = (const float*)d_in[5];
  const float* qkv_w = (const float*)d_in[6];
  const float* proj_w = (const float*)d_in[7];
  const float* cpb_w1 = (const float*)d_in[8];
  const float* cpb_b1 = (const float*)d_in[9];
  const float* cpb_w2 = (const float*)d_in[10];
  const float* fc1_w = (const float*)d_in[11];
  const float* fc2_w = (const float*)d_in[12];
  float* outp = (float*)d_out;
  char* ws = (char*)d_ws;

  u16* wq = (u16*)(ws + 0);              // 1536x512 bf16 (q cols pre-scaled)
  u16* wp = (u16*)(ws + 1572864);        // 512x512
  u16* w1 = (u16*)(ws + 2097152);        // 2048x512 (permuted)
  u16* w2 = (u16*)(ws + 4194304);        // 512x1024
  float* tab2 = (float*)(ws + 5242880);  // 16x961 f32 (pre-shifted)
  const size_t RB = 67108864;
  u16* R0 = (u16*)(ws + 8388608);            // xwbuf (proj residual)
  u16* R1 = (u16*)(ws + 8388608 + RB);       // r1
  u16* R2 = (u16*)(ws + 8388608 + 2 * RB);   // hbuf -> obuf
  u16* R3 = (u16*)(ws + 8388608 + 3 * RB);   // qkv (201MB, spans R3..R5) -> h2
  u16* R4 = (u16*)(ws + 8388608 + 4 * RB);   // gbuf (134MB, spans R4+R5)

  head_kernel<<<13249, 256, 0, stream>>>(x, n1w, n1b, R2, R0,
                                         qkv_w, proj_w, fc1_w, fc2_w,
                                         rel_table, cpb_w1, cpb_b1, cpb_w2,
                                         wq, wp, w1, w2, tab2);
  gemm_bt<0><<<6144, 256, 0, stream>>>(R2, wq, R3, nullptr,
                                       nullptr, nullptr, 65536, 1536, 512);
  attn_kernel<<<dim3(16, 256), 256, 0, stream>>>(R3, tab2, R2);
  gemm_bt<1><<<2048, 256, 0, stream>>>(R2, wp, R1, R0,
                                       nullptr, nullptr, 65536, 512, 512);
  ln2_kernel<<<16384, 256, 0, stream>>>(R1, n2w, n2b, R3);
  gemm_bt<3><<<8192, 256, 0, stream>>>(R3, w1, R4, nullptr,
                                       nullptr, nullptr, 65536, 2048, 512);
  gemm_bt<4><<<2048, 256, 0, stream>>>(R4, w2, nullptr, R1,
                                       x, outp, 65536, 512, 1024);
}

// Round 13
// 745.957 us; speedup vs baseline: 1.0742x; 1.0742x over previous
//
#include <hip/hip_runtime.h>
#include <hip/hip_bf16.h>

typedef unsigned short u16;
typedef unsigned int u32;
typedef __attribute__((ext_vector_type(8))) u16 u16x8;
typedef __attribute__((ext_vector_type(4))) u16 u16x4;
typedef __attribute__((ext_vector_type(8))) short bf16x8;
typedef __attribute__((ext_vector_type(4))) float f32x4;

__device__ __forceinline__ u16 f2bf(float f) {
  u32 u = __float_as_uint(f);
  u += 0x7fffu + ((u >> 16) & 1u);
  return (u16)(u >> 16);
}
__device__ __forceinline__ float bf2f(u16 h) {
  return __uint_as_float(((u32)h) << 16);
}
__device__ __forceinline__ u16 cvt_bf(float f) {
  __hip_bfloat16 h(f);
  return __builtin_bit_cast(u16, h);
}
__device__ __forceinline__ bf16x8 ld_bf8(const u16* p) {
  return __builtin_bit_cast(bf16x8, *(const u16x8*)p);
}

#if __has_builtin(__builtin_amdgcn_exp2f)
#define EXP2(x) __builtin_amdgcn_exp2f(x)
#else
#define EXP2(x) exp2f(x)
#endif

typedef const void __attribute__((address_space(1)))* gas_t;
typedef void __attribute__((address_space(3)))* las_t;
#define GLOAD_LDS16(gp, lp) __builtin_amdgcn_global_load_lds((gas_t)(gp), (las_t)(lp), 16, 0, 0)

#define QSCALE 0.25503486f       // (1/sqrt(32)) * log2(e), folded into wq q-columns
#define BIAS_MUL 23.08312065f    // 16 * log2(e)

// ---------------- fused head: LN1 (blocks [0,2048)) + weight prep + CPB (blocks [2048,13249)) ----------------
__global__ __launch_bounds__(256, 4) void head_kernel(
    const float* __restrict__ x, const float* __restrict__ n1w, const float* __restrict__ n1b,
    u16* __restrict__ hbuf, u16* __restrict__ xwbuf,
    const float* __restrict__ qkv_w, const float* __restrict__ proj_w,
    const float* __restrict__ fc1_w, const float* __restrict__ fc2_w,
    const float* __restrict__ rt, const float* __restrict__ cw1,
    const float* __restrict__ cb1, const float* __restrict__ cw2,
    u16* __restrict__ wq, u16* __restrict__ wp, u16* __restrict__ w1,
    u16* __restrict__ w2, float* __restrict__ tab2) {
  __shared__ u16 tile[512 * 33];
  __shared__ float red[2][8][32];
  __shared__ float meanv[32], rstdv[32];
  int blk = blockIdx.x, t = threadIdx.x;
  if (blk < 2048) {
    // ---- LN1: 32 pixels per block (R8-proven) ----
    int bi = blk;
    int bimg = bi >> 7, rest = bi & 127, hrow = rest >> 1, half = rest & 1;
    int p = t & 31, g = t >> 5;
    const float* xr = x + (size_t)bimg * 512 * 4096 + (size_t)hrow * 64 + half * 32;
    float s = 0.f, s2 = 0.f;
    for (int i = 0; i < 64; ++i) {
      int c = g * 64 + i;
      float v = xr[(size_t)c * 4096 + p];
      tile[c * 33 + p] = f2bf(v);
      s += v; s2 += v * v;
    }
    red[0][g][p] = s; red[1][g][p] = s2;
    __syncthreads();
    if (t < 32) {
      float ss = 0.f, qq = 0.f;
      for (int gg = 0; gg < 8; ++gg) { ss += red[0][gg][t]; qq += red[1][gg][t]; }
      float mu = ss * (1.f / 512.f);
      float var = qq * (1.f / 512.f) - mu * mu;
      meanv[t] = mu;
      rstdv[t] = rsqrtf(var + 1e-5f);
    }
    __syncthreads();
    int c0 = t * 2;
    float w0 = n1w[c0], w1v = n1w[c0 + 1], b0 = n1b[c0], b1v = n1b[c0 + 1];
    int hy = hrow >> 4, iy = hrow & 15;
    for (int pp = 0; pp < 32; ++pp) {
      int pixel = half * 32 + pp;
      int wx = pixel >> 4, ix = pixel & 15;
      int widx = bimg * 16 + hy * 4 + wx;
      size_t basep = ((size_t)widx * 256 + iy * 16 + ix) * 512;
      u16 rb0 = tile[c0 * 33 + pp], rb1 = tile[(c0 + 1) * 33 + pp];
      float mu = meanv[pp], rs = rstdv[pp];
      float v0 = bf2f(rb0), v1 = bf2f(rb1);
      *(u32*)(xwbuf + basep + c0) = (u32)rb0 | ((u32)rb1 << 16);
      u16 h0 = f2bf((v0 - mu) * rs * w0 + b0);
      u16 h1 = f2bf((v1 - mu) * rs * w1v + b1v);
      *(u32*)(hbuf + basep + c0) = (u32)h0 | ((u32)h1 << 16);
    }
    return;
  }
  int b = blk - 2048;
  if (b < 3072) {
    int idx = b * 256 + t;  // qkv transpose, q cols pre-scaled
    int n = idx >> 9, k = idx & 511;
    float s = n < 512 ? QSCALE : 1.f;
    wq[idx] = f2bf(qkv_w[(size_t)k * 1536 + n] * s);
  } else if (b < 4096) {
    int idx = (b - 3072) * 256 + t;
    int n = idx >> 9, k = idx & 511;
    wp[idx] = f2bf(proj_w[(size_t)k * 512 + n]);
  } else if (b < 8192) {
    int idx = (b - 4096) * 256 + t;  // fc1 permuted
    int n = idx >> 9, k = idx & 511;
    int i = ((n >> 5) << 4) | (n & 15);
    int gsel = (n >> 4) & 1;
    w1[idx] = f2bf(fc1_w[(size_t)k * 2048 + i + gsel * 1024]);
  } else if (b < 10240) {
    int idx = (b - 8192) * 256 + t;  // fc2: N=512, K=1024
    int n = idx >> 10, k = idx & 1023;
    w2[idx] = f2bf(fc2_w[(size_t)k * 512 + n]);
  } else {
    // CPB MLP; alias ln1's shared arrays
    float* hid = (float*)tile;                         // 512 f32
    float (*part)[17] = (float (*)[17])(tile + 4096);  // 16x17 f32
    int tix = b - 10240;  // 0..960
    float r0 = rt[tix * 2], r1 = rt[tix * 2 + 1];
    for (int j = t; j < 512; j += 256) {
      float v = r0 * cw1[j] + r1 * cw1[512 + j] + cb1[j];
      hid[j] = v > 0.f ? v : 0.f;
    }
    __syncthreads();
    int hh = t & 15, seg = t >> 4;
    float acc = 0.f;
    for (int j = seg * 32; j < seg * 32 + 32; ++j) acc += hid[j] * cw2[j * 16 + hh];
    part[seg][hh] = acc;
    __syncthreads();
    if (t < 16) {
      float s = 0.f;
      for (int g = 0; g < 16; ++g) s += part[g][t];
      tab2[t * 961 + tix] = BIAS_MUL / (1.f + __expf(-s)) - 23.0f;
    }
  }
}

// ---------------- 128x128 bf16 MFMA GEMM (R5/R8 proven), XCD-panel mapping ----------------
// EPI: 0 plain bf16 [row][N], 1 out = acc + res(bf16), 3 fused SwiGLU (permuted w1),
//      4 fused final: out_f32(CHW) = acc + res(bf16 token-major) + x(f32 CHW)
template <int EPI>
__global__ __launch_bounds__(256, 4) void gemm_bt(
    const u16* __restrict__ A, const u16* __restrict__ Bt,
    u16* __restrict__ out, const u16* __restrict__ res,
    const float* __restrict__ xg, float* __restrict__ outf,
    int M, int N, int K) {
  __shared__ u16 As[128 * 64];
  __shared__ u16 Bs[128 * 64];
  const int t = threadIdx.x, l = t & 63, wv = t >> 6;
  const int nbx = N >> 7;
  const int wg = (int)blockIdx.x;
  const int xcd = wg & 7, c = wg >> 3;
  const int cm = c / nbx;
  const int m0 = (xcd * 64 + cm) * 128, n0 = (c - cm * nbx) * 128;
  const int wr = wv >> 1, wc = wv & 1;
  const int lr = l & 15, lk = l >> 4;
  f32x4 acc[4][4] = {};
  for (int kt = 0; kt < K; kt += 64) {
#pragma unroll
    for (int j = 0; j < 4; ++j) {
      int qi = j * 256 + t;
      int r = qi >> 3, c8 = (qi & 7) * 8;
      GLOAD_LDS16(A + (size_t)(m0 + r) * K + kt + c8, As + (size_t)(j * 256 + wv * 64) * 8);
    }
#pragma unroll
    for (int j = 0; j < 4; ++j) {
      int qi = j * 256 + t;
      int r = qi >> 3, c8 = (qi & 7) * 8;
      GLOAD_LDS16(Bt + (size_t)(n0 + r) * K + kt + c8, Bs + (size_t)(j * 256 + wv * 64) * 8);
    }
    __syncthreads();
#pragma unroll
    for (int ks = 0; ks < 2; ++ks) {
      bf16x8 a[4], bb[4];
#pragma unroll
      for (int mf = 0; mf < 4; ++mf)
        a[mf] = ld_bf8(As + (wr * 64 + mf * 16 + lr) * 64 + ks * 32 + lk * 8);
#pragma unroll
      for (int nf = 0; nf < 4; ++nf)
        bb[nf] = ld_bf8(Bs + (wc * 64 + nf * 16 + lr) * 64 + ks * 32 + lk * 8);
#pragma unroll
      for (int mf = 0; mf < 4; ++mf)
#pragma unroll
        for (int nf = 0; nf < 4; ++nf)
          acc[mf][nf] = __builtin_amdgcn_mfma_f32_16x16x32_bf16(a[mf], bb[nf], acc[mf][nf], 0, 0, 0);
    }
    __syncthreads();
  }
#pragma unroll
  for (int mf = 0; mf < 4; ++mf) {
    int rbase = m0 + wr * 64 + mf * 16 + lk * 4;
    if constexpr (EPI == 3) {
#pragma unroll
      for (int nf = 0; nf < 4; nf += 2) {
        int colv = n0 + wc * 64 + nf * 16 + lr;
        int i = ((colv >> 5) << 4) | (colv & 15);
#pragma unroll
        for (int jj = 0; jj < 4; ++jj) {
          int row = rbase + jj;
          float val = acc[mf][nf][jj], gate = acc[mf][nf + 1][jj];
          float sil = gate / (1.f + __expf(-gate));
          out[(size_t)row * 1024 + i] = f2bf(sil * val);
        }
      }
    } else if constexpr (EPI == 4) {
      int widx = rbase >> 8, iy = (rbase >> 4) & 15, ix0 = rbase & 15;
      int bimg = widx >> 4, hy = (widx >> 2) & 3, wx = widx & 3;
#pragma unroll
      for (int nf = 0; nf < 4; ++nf) {
        int col = n0 + wc * 64 + nf * 16 + lr;
        size_t obase = (((size_t)(bimg * 512 + col) * 64) + hy * 16 + iy) * 64 + wx * 16 + ix0;
        const float* xp = xg + obase;
        float* op = outf + obase;
#pragma unroll
        for (int jj = 0; jj < 4; ++jj)
          op[jj] = acc[mf][nf][jj] + bf2f(res[(size_t)(rbase + jj) * 512 + col]) + xp[jj];
      }
    } else if constexpr (EPI == 1) {
#pragma unroll
      for (int nf = 0; nf < 4; ++nf) {
        int col = n0 + wc * 64 + nf * 16 + lr;
#pragma unroll
        for (int jj = 0; jj < 4; ++jj) {
          int row = rbase + jj;
          out[(size_t)row * N + col] = f2bf(acc[mf][nf][jj] + bf2f(res[(size_t)row * N + col]));
        }
      }
    } else {
#pragma unroll
      for (int nf = 0; nf < 4; ++nf) {
        int col = n0 + wc * 64 + nf * 16 + lr;
#pragma unroll
        for (int jj = 0; jj < 4; ++jj)
          out[(size_t)(rbase + jj) * N + col] = f2bf(acc[mf][nf][jj]);
      }
    }
  }
}

// ---------------- windowed flash attention (R10/R11 proven), qkv natural layout [tok][1536] ----------------
__global__ __launch_bounds__(256, 4) void attn_kernel(
    const u16* __restrict__ qkv, const float* __restrict__ tab2, u16* __restrict__ ob) {
  __shared__ u16 vt[32 * 72];
  __shared__ float tabh4[31 * 32 * 4];
  __shared__ u16 pl[4][16 * 76];
  const int h = blockIdx.x, w = blockIdx.y;
  const int t = threadIdx.x, l = t & 63, wid = t >> 6;
  const u16* qg = qkv + (size_t)(w * 256) * 1536 + h * 32;
  const u16* kg = qg + 512;
  const u16* vg = qg + 1024;
  const float* th = tab2 + h * 961;
  for (int i = t; i < 992; i += 256) {
    int dy = i >> 5, dx = i & 31;
#pragma unroll
    for (int r = 0; r < 4; ++r) {
      int dxr = dx + r;
      tabh4[i * 4 + r] = (dxr <= 30) ? th[dy * 31 + dxr] : 0.f;
    }
  }
  const int q4 = l >> 4, c0 = l & 15;
  const int dx0 = q4 * 4 - c0 + 15;
  bf16x8 qa[4];
#pragma unroll
  for (int mf = 0; mf < 4; ++mf)
    qa[mf] = ld_bf8(qg + (size_t)(wid * 64 + mf * 16 + c0) * 1536 + q4 * 8);
  f32x4 oacc[4][2] = {};
  float psum[4][4] = {};
  for (int ct = 0; ct < 4; ++ct) {
    {
      int r = t & 63, j = t >> 6;
      u16x8 dv = *(const u16x8*)(vg + (size_t)(ct * 64 + r) * 1536 + j * 8);
#pragma unroll
      for (int e = 0; e < 8; ++e) vt[(j * 8 + e) * 72 + r] = dv[e];
    }
    __syncthreads();
    bf16x8 bfr[4];
#pragma unroll
    for (int nf = 0; nf < 4; ++nf)
      bfr[nf] = ld_bf8(kg + (size_t)(ct * 64 + nf * 16 + c0) * 1536 + q4 * 8);
    bf16x8 vfr[2][2];
#pragma unroll
    for (int df = 0; df < 2; ++df)
#pragma unroll
      for (int ks2 = 0; ks2 < 2; ++ks2)
        vfr[df][ks2] = ld_bf8(vt + (df * 16 + c0) * 72 + ks2 * 32 + q4 * 8);
#pragma unroll
    for (int mf = 0; mf < 4; ++mf) {
      const int dyb = wid * 4 + mf - ct * 4 + 15;
      f32x4 sacc[4];
#pragma unroll
      for (int nf = 0; nf < 4; ++nf)
        sacc[nf] = *(const f32x4*)&tabh4[((dyb - nf) * 32 + dx0) * 4];
      __builtin_amdgcn_s_setprio(1);
#pragma unroll
      for (int nf = 0; nf < 4; ++nf)
        sacc[nf] = __builtin_amdgcn_mfma_f32_16x16x32_bf16(qa[mf], bfr[nf], sacc[nf], 0, 0, 0);
      __builtin_amdgcn_s_setprio(0);
#pragma unroll
      for (int nf = 0; nf < 4; ++nf) {
#pragma unroll
        for (int jj = 0; jj < 4; ++jj) {
          float p = EXP2(sacc[nf][jj]);
          psum[mf][jj] += p;
          pl[wid][(q4 * 4 + jj) * 76 + nf * 16 + c0] = cvt_bf(p);
        }
      }
      __builtin_amdgcn_s_setprio(1);
#pragma unroll
      for (int ks2 = 0; ks2 < 2; ++ks2) {
        bf16x8 pa = ld_bf8(&pl[wid][c0 * 76 + ks2 * 32 + q4 * 8]);
        oacc[mf][0] = __builtin_amdgcn_mfma_f32_16x16x32_bf16(pa, vfr[0][ks2], oacc[mf][0], 0, 0, 0);
        oacc[mf][1] = __builtin_amdgcn_mfma_f32_16x16x32_bf16(pa, vfr[1][ks2], oacc[mf][1], 0, 0, 0);
      }
      __builtin_amdgcn_s_setprio(0);
    }
    __syncthreads();
  }
#pragma unroll
  for (int mf = 0; mf < 4; ++mf) {
#pragma unroll
    for (int jj = 0; jj < 4; ++jj) {
      float s = psum[mf][jj];
      s += __shfl_xor(s, 1);
      s += __shfl_xor(s, 2);
      s += __shfl_xor(s, 4);
      s += __shfl_xor(s, 8);
      float inv = 1.f / s;
      int row = wid * 64 + mf * 16 + q4 * 4 + jj;
      size_t obase = ((size_t)w * 256 + row) * 512 + h * 32;
      ob[obase + c0] = f2bf(oacc[mf][0][jj] * inv);
      ob[obase + 16 + c0] = f2bf(oacc[mf][1][jj] * inv);
    }
  }
}

// ---------------- LN2 ----------------
__global__ __launch_bounds__(256, 4) void ln2_kernel(const u16* __restrict__ r1,
    const float* __restrict__ w, const float* __restrict__ b, u16* __restrict__ h2) {
  int t = threadIdx.x, l = t & 63, wid = t >> 6;
  size_t token = (size_t)blockIdx.x * 4 + wid;
  const u16* rp = r1 + token * 512 + l * 8;
  u16x8 raw = *(const u16x8*)rp;
  float v[8]; float s = 0.f, s2 = 0.f;
#pragma unroll
  for (int i = 0; i < 8; ++i) { v[i] = bf2f(raw[i]); s += v[i]; s2 += v[i] * v[i]; }
#pragma unroll
  for (int m = 1; m < 64; m <<= 1) { s += __shfl_xor(s, m); s2 += __shfl_xor(s2, m); }
  float mu = s * (1.f / 512.f);
  float var = s2 * (1.f / 512.f) - mu * mu;
  float rs = rsqrtf(var + 1e-5f);
  u16x8 o;
#pragma unroll
  for (int i = 0; i < 8; ++i) {
    int c = l * 8 + i;
    o[i] = f2bf((v[i] - mu) * rs * w[c] + b[c]);
  }
  *(u16x8*)(h2 + token * 512 + l * 8) = o;
}

extern "C" void kernel_launch(void* const* d_in, const int* in_sizes, int n_in,
                              void* d_out, int out_size, void* d_ws, size_t ws_size,
                              hipStream_t stream) {
  (void)in_sizes; (void)n_in; (void)out_size; (void)ws_size;
  const float* x = (const float*)d_in[0];
  const float* rel_table = (const float*)d_in[1];
  const float* n1w = (const float*)d_in[2];
  const float* n1b = (const float*)d_in[3];
  const float* n2w = (const float*)d_in[4];
  const float* n2b = (const float*)d_in[5];
  const float* qkv_w = (const float*)d_in[6];
  const float* proj_w = (const float*)d_in[7];
  const float* cpb_w1 = (const float*)d_in[8];
  const float* cpb_b1 = (const float*)d_in[9];
  const float* cpb_w2 = (const float*)d_in[10];
  const float* fc1_w = (const float*)d_in[11];
  const float* fc2_w = (const float*)d_in[12];
  float* outp = (float*)d_out;
  char* ws = (char*)d_ws;

  u16* wq = (u16*)(ws + 0);              // 1536x512 bf16 (q cols pre-scaled)
  u16* wp = (u16*)(ws + 1572864);        // 512x512
  u16* w1 = (u16*)(ws + 2097152);        // 2048x512 (permuted)
  u16* w2 = (u16*)(ws + 4194304);        // 512x1024
  float* tab2 = (float*)(ws + 5242880);  // 16x961 f32 (pre-shifted)
  const size_t RB = 67108864;
  u16* R0 = (u16*)(ws + 8388608);            // xwbuf (proj residual)
  u16* R1 = (u16*)(ws + 8388608 + RB);       // r1
  u16* R2 = (u16*)(ws + 8388608 + 2 * RB);   // hbuf -> obuf
  u16* R3 = (u16*)(ws + 8388608 + 3 * RB);   // qkv (201MB, spans R3..R5) -> h2
  u16* R4 = (u16*)(ws + 8388608 + 4 * RB);   // gbuf (134MB, spans R4+R5)

  head_kernel<<<13249, 256, 0, stream>>>(x, n1w, n1b, R2, R0,
                                         qkv_w, proj_w, fc1_w, fc2_w,
                                         rel_table, cpb_w1, cpb_b1, cpb_w2,
                                         wq, wp, w1, w2, tab2);
  gemm_bt<0><<<6144, 256, 0, stream>>>(R2, wq, R3, nullptr,
                                       nullptr, nullptr, 65536, 1536, 512);
  attn_kernel<<<dim3(16, 256), 256, 0, stream>>>(R3, tab2, R2);
  gemm_bt<1><<<2048, 256, 0, stream>>>(R2, wp, R1, R0,
                                       nullptr, nullptr, 65536, 512, 512);
  ln2_kernel<<<16384, 256, 0, stream>>>(R1, n2w, n2b, R3);
  gemm_bt<3><<<8192, 256, 0, stream>>>(R3, w1, R4, nullptr,
                                       nullptr, nullptr, 65536, 2048, 512);
  gemm_bt<4><<<2048, 256, 0, stream>>>(R4, w2, nullptr, R1,
                                       x, outp, 65536, 512, 1024);
}

// Round 14
// 721.734 us; speedup vs baseline: 1.1103x; 1.0336x over previous
//
#include <hip/hip_runtime.h>
#include <hip/hip_bf16.h>

typedef unsigned short u16;
typedef unsigned int u32;
typedef __attribute__((ext_vector_type(8))) u16 u16x8;
typedef __attribute__((ext_vector_type(4))) u16 u16x4;
typedef __attribute__((ext_vector_type(8))) short bf16x8;
typedef __attribute__((ext_vector_type(4))) float f32x4;

__device__ __forceinline__ u16 f2bf(float f) {
  u32 u = __float_as_uint(f);
  u += 0x7fffu + ((u >> 16) & 1u);
  return (u16)(u >> 16);
}
__device__ __forceinline__ float bf2f(u16 h) {
  return __uint_as_float(((u32)h) << 16);
}
__device__ __forceinline__ u16 cvt_bf(float f) {
  __hip_bfloat16 h(f);
  return __builtin_bit_cast(u16, h);
}
__device__ __forceinline__ bf16x8 ld_bf8(const u16* p) {
  return __builtin_bit_cast(bf16x8, *(const u16x8*)p);
}

#if __has_builtin(__builtin_amdgcn_exp2f)
#define EXP2(x) __builtin_amdgcn_exp2f(x)
#else
#define EXP2(x) exp2f(x)
#endif

typedef const void __attribute__((address_space(1)))* gas_t;
typedef void __attribute__((address_space(3)))* las_t;
#define GLOAD_LDS16(gp, lp) __builtin_amdgcn_global_load_lds((gas_t)(gp), (las_t)(lp), 16, 0, 0)

#define QSCALE 0.25503486f       // (1/sqrt(32)) * log2(e), folded into wq q-columns
#define BIAS_MUL 23.08312065f    // 16 * log2(e)

// ---------------- fused head: LN1 [0,2048) + weight prep + CPB-scatter [2048,13249) ----------------
// CPB blocks scatter their per-head values straight into the frag-replicated global table
// tabh4g[h][i=dy*32+dx][r] = tab(h, dy*31+dx+r); out-of-range (dx+r>30) entries stay 0 (memset).
__global__ __launch_bounds__(256, 4) void head_kernel(
    const float* __restrict__ x, const float* __restrict__ n1w, const float* __restrict__ n1b,
    u16* __restrict__ hbuf, u16* __restrict__ xwbuf,
    const float* __restrict__ qkv_w, const float* __restrict__ proj_w,
    const float* __restrict__ fc1_w, const float* __restrict__ fc2_w,
    const float* __restrict__ rt, const float* __restrict__ cw1,
    const float* __restrict__ cb1, const float* __restrict__ cw2,
    u16* __restrict__ wq, u16* __restrict__ wp, u16* __restrict__ w1,
    u16* __restrict__ w2, float* __restrict__ tabh4g) {
  __shared__ u16 tile[512 * 33];
  __shared__ float red[2][8][32];
  __shared__ float meanv[32], rstdv[32];
  int blk = blockIdx.x, t = threadIdx.x;
  if (blk < 2048) {
    // ---- LN1: 32 pixels per block (R8-proven) ----
    int bi = blk;
    int bimg = bi >> 7, rest = bi & 127, hrow = rest >> 1, half = rest & 1;
    int p = t & 31, g = t >> 5;
    const float* xr = x + (size_t)bimg * 512 * 4096 + (size_t)hrow * 64 + half * 32;
    float s = 0.f, s2 = 0.f;
    for (int i = 0; i < 64; ++i) {
      int c = g * 64 + i;
      float v = xr[(size_t)c * 4096 + p];
      tile[c * 33 + p] = f2bf(v);
      s += v; s2 += v * v;
    }
    red[0][g][p] = s; red[1][g][p] = s2;
    __syncthreads();
    if (t < 32) {
      float ss = 0.f, qq = 0.f;
      for (int gg = 0; gg < 8; ++gg) { ss += red[0][gg][t]; qq += red[1][gg][t]; }
      float mu = ss * (1.f / 512.f);
      float var = qq * (1.f / 512.f) - mu * mu;
      meanv[t] = mu;
      rstdv[t] = rsqrtf(var + 1e-5f);
    }
    __syncthreads();
    int c0 = t * 2;
    float w0 = n1w[c0], w1v = n1w[c0 + 1], b0 = n1b[c0], b1v = n1b[c0 + 1];
    int hy = hrow >> 4, iy = hrow & 15;
    for (int pp = 0; pp < 32; ++pp) {
      int pixel = half * 32 + pp;
      int wx = pixel >> 4, ix = pixel & 15;
      int widx = bimg * 16 + hy * 4 + wx;
      size_t basep = ((size_t)widx * 256 + iy * 16 + ix) * 512;
      u16 rb0 = tile[c0 * 33 + pp], rb1 = tile[(c0 + 1) * 33 + pp];
      float mu = meanv[pp], rs = rstdv[pp];
      float v0 = bf2f(rb0), v1 = bf2f(rb1);
      *(u32*)(xwbuf + basep + c0) = (u32)rb0 | ((u32)rb1 << 16);
      u16 h0 = f2bf((v0 - mu) * rs * w0 + b0);
      u16 h1 = f2bf((v1 - mu) * rs * w1v + b1v);
      *(u32*)(hbuf + basep + c0) = (u32)h0 | ((u32)h1 << 16);
    }
    return;
  }
  int b = blk - 2048;
  if (b < 3072) {
    int idx = b * 256 + t;  // qkv transpose, q cols pre-scaled
    int n = idx >> 9, k = idx & 511;
    float s = n < 512 ? QSCALE : 1.f;
    wq[idx] = f2bf(qkv_w[(size_t)k * 1536 + n] * s);
  } else if (b < 4096) {
    int idx = (b - 3072) * 256 + t;
    int n = idx >> 9, k = idx & 511;
    wp[idx] = f2bf(proj_w[(size_t)k * 512 + n]);
  } else if (b < 8192) {
    int idx = (b - 4096) * 256 + t;  // fc1 permuted
    int n = idx >> 9, k = idx & 511;
    int i = ((n >> 5) << 4) | (n & 15);
    int gsel = (n >> 4) & 1;
    w1[idx] = f2bf(fc1_w[(size_t)k * 2048 + i + gsel * 1024]);
  } else if (b < 10240) {
    int idx = (b - 8192) * 256 + t;  // fc2: N=512, K=1024
    int n = idx >> 10, k = idx & 1023;
    w2[idx] = f2bf(fc2_w[(size_t)k * 512 + n]);
  } else {
    // CPB MLP for one table entry tix; scatter per-head values into tabh4g
    float* hid = (float*)tile;                         // 512 f32
    float (*part)[17] = (float (*)[17])(tile + 4096);  // 16x17 f32
    int tix = b - 10240;  // 0..960
    float r0 = rt[tix * 2], r1 = rt[tix * 2 + 1];
    for (int j = t; j < 512; j += 256) {
      float v = r0 * cw1[j] + r1 * cw1[512 + j] + cb1[j];
      hid[j] = v > 0.f ? v : 0.f;
    }
    __syncthreads();
    int hh = t & 15, seg = t >> 4;
    float acc = 0.f;
    for (int j = seg * 32; j < seg * 32 + 32; ++j) acc += hid[j] * cw2[j * 16 + hh];
    part[seg][hh] = acc;
    __syncthreads();
    if (t < 16) {
      float s = 0.f;
      for (int g = 0; g < 16; ++g) s += part[g][t];
      float val = BIAS_MUL / (1.f + __expf(-s)) - 23.0f;
      int dy = tix / 31, c = tix - dy * 31;  // tix = dy*31 + c
#pragma unroll
      for (int r = 0; r < 4; ++r) {
        int dx = c - r;
        if (dx >= 0)
          tabh4g[((size_t)t * 992 + dy * 32 + dx) * 4 + r] = val;
      }
    }
  }
}

// ---------------- 128x128 bf16 MFMA GEMM + T2 seg-XOR swizzle (R9-verified math), XCD-panel map ----------------
// Stage: pre-swizzled global source, linear LDS dest. Read: chunk ^ (lr&7). Conflicts 5e7 -> ~0.
// EPI: 0 plain bf16 [row][N], 1 out = acc + res(bf16), 3 fused SwiGLU (permuted w1),
//      4 fused final: out_f32(CHW) = acc + res(bf16 token-major) + x(f32 CHW)
template <int EPI>
__global__ __launch_bounds__(256, 4) void gemm_bt(
    const u16* __restrict__ A, const u16* __restrict__ Bt,
    u16* __restrict__ out, const u16* __restrict__ res,
    const float* __restrict__ xg, float* __restrict__ outf,
    int M, int N, int K) {
  __shared__ u16 As[128 * 64];
  __shared__ u16 Bs[128 * 64];
  const int t = threadIdx.x, l = t & 63, wv = t >> 6;
  const int nbx = N >> 7;
  const int wg = (int)blockIdx.x;
  const int xcd = wg & 7, c = wg >> 3;
  const int cm = c / nbx;
  const int m0 = (xcd * 64 + cm) * 128, n0 = (c - cm * nbx) * 128;
  const int wr = wv >> 1, wc = wv & 1;
  const int lr = l & 15, lk = l >> 4;
  const int swz = lr & 7;
  f32x4 acc[4][4] = {};
  for (int kt = 0; kt < K; kt += 64) {
#pragma unroll
    for (int j = 0; j < 4; ++j) {
      int qi = j * 256 + t;
      int r = qi >> 3, s = qi & 7;
      int c8 = (s ^ (r & 7)) * 8;  // pre-swizzled source chunk
      GLOAD_LDS16(A + (size_t)(m0 + r) * K + kt + c8, As + (size_t)qi * 8);
    }
#pragma unroll
    for (int j = 0; j < 4; ++j) {
      int qi = j * 256 + t;
      int r = qi >> 3, s = qi & 7;
      int c8 = (s ^ (r & 7)) * 8;
      GLOAD_LDS16(Bt + (size_t)(n0 + r) * K + kt + c8, Bs + (size_t)qi * 8);
    }
    __syncthreads();
#pragma unroll
    for (int ks = 0; ks < 2; ++ks) {
      bf16x8 a[4], bb[4];
#pragma unroll
      for (int mf = 0; mf < 4; ++mf)
        a[mf] = ld_bf8(As + (wr * 64 + mf * 16 + lr) * 64 + (((ks * 4 + lk) ^ swz) << 3));
#pragma unroll
      for (int nf = 0; nf < 4; ++nf)
        bb[nf] = ld_bf8(Bs + (wc * 64 + nf * 16 + lr) * 64 + (((ks * 4 + lk) ^ swz) << 3));
#pragma unroll
      for (int mf = 0; mf < 4; ++mf)
#pragma unroll
        for (int nf = 0; nf < 4; ++nf)
          acc[mf][nf] = __builtin_amdgcn_mfma_f32_16x16x32_bf16(a[mf], bb[nf], acc[mf][nf], 0, 0, 0);
    }
    __syncthreads();
  }
#pragma unroll
  for (int mf = 0; mf < 4; ++mf) {
    int rbase = m0 + wr * 64 + mf * 16 + lk * 4;
    if constexpr (EPI == 3) {
#pragma unroll
      for (int nf = 0; nf < 4; nf += 2) {
        int colv = n0 + wc * 64 + nf * 16 + lr;
        int i = ((colv >> 5) << 4) | (colv & 15);
#pragma unroll
        for (int jj = 0; jj < 4; ++jj) {
          int row = rbase + jj;
          float val = acc[mf][nf][jj], gate = acc[mf][nf + 1][jj];
          float sil = gate / (1.f + __expf(-gate));
          out[(size_t)row * 1024 + i] = f2bf(sil * val);
        }
      }
    } else if constexpr (EPI == 4) {
      int widx = rbase >> 8, iy = (rbase >> 4) & 15, ix0 = rbase & 15;
      int bimg = widx >> 4, hy = (widx >> 2) & 3, wx = widx & 3;
#pragma unroll
      for (int nf = 0; nf < 4; ++nf) {
        int col = n0 + wc * 64 + nf * 16 + lr;
        size_t obase = (((size_t)(bimg * 512 + col) * 64) + hy * 16 + iy) * 64 + wx * 16 + ix0;
        const float* xp = xg + obase;
        float* op = outf + obase;
#pragma unroll
        for (int jj = 0; jj < 4; ++jj)
          op[jj] = acc[mf][nf][jj] + bf2f(res[(size_t)(rbase + jj) * 512 + col]) + xp[jj];
      }
    } else if constexpr (EPI == 1) {
#pragma unroll
      for (int nf = 0; nf < 4; ++nf) {
        int col = n0 + wc * 64 + nf * 16 + lr;
#pragma unroll
        for (int jj = 0; jj < 4; ++jj) {
          int row = rbase + jj;
          out[(size_t)row * N + col] = f2bf(acc[mf][nf][jj] + bf2f(res[(size_t)row * N + col]));
        }
      }
    } else {
#pragma unroll
      for (int nf = 0; nf < 4; ++nf) {
        int col = n0 + wc * 64 + nf * 16 + lr;
#pragma unroll
        for (int jj = 0; jj < 4; ++jj)
          out[(size_t)(rbase + jj) * N + col] = f2bf(acc[mf][nf][jj]);
      }
    }
  }
}

// ---------------- windowed flash attention (R10/R11 proven), precomputed bias table ----------------
__global__ __launch_bounds__(256, 4) void attn_kernel(
    const u16* __restrict__ qkv, const float* __restrict__ tabh4g, u16* __restrict__ ob) {
  __shared__ u16 vt[32 * 72];
  __shared__ float tabh4[31 * 32 * 4];
  __shared__ u16 pl[4][16 * 76];
  const int h = blockIdx.x, w = blockIdx.y;
  const int t = threadIdx.x, l = t & 63, wid = t >> 6;
  const u16* qg = qkv + (size_t)(w * 256) * 1536 + h * 32;
  const u16* kg = qg + 512;
  const u16* vg = qg + 1024;
  // coalesced copy of the frag-replicated bias table (built once in head_kernel)
  const float* tg = tabh4g + (size_t)h * 992 * 4;
  for (int i = t; i < 992; i += 256)
    *(f32x4*)&tabh4[i * 4] = *(const f32x4*)(tg + (size_t)i * 4);
  const int q4 = l >> 4, c0 = l & 15;
  const int dx0 = q4 * 4 - c0 + 15;
  bf16x8 qa[4];
#pragma unroll
  for (int mf = 0; mf < 4; ++mf)
    qa[mf] = ld_bf8(qg + (size_t)(wid * 64 + mf * 16 + c0) * 1536 + q4 * 8);
  f32x4 oacc[4][2] = {};
  float psum[4][4] = {};
  for (int ct = 0; ct < 4; ++ct) {
    {
      int r = t & 63, j = t >> 6;
      u16x8 dv = *(const u16x8*)(vg + (size_t)(ct * 64 + r) * 1536 + j * 8);
#pragma unroll
      for (int e = 0; e < 8; ++e) vt[(j * 8 + e) * 72 + r] = dv[e];
    }
    __syncthreads();
    bf16x8 bfr[4];
#pragma unroll
    for (int nf = 0; nf < 4; ++nf)
      bfr[nf] = ld_bf8(kg + (size_t)(ct * 64 + nf * 16 + c0) * 1536 + q4 * 8);
    bf16x8 vfr[2][2];
#pragma unroll
    for (int df = 0; df < 2; ++df)
#pragma unroll
      for (int ks2 = 0; ks2 < 2; ++ks2)
        vfr[df][ks2] = ld_bf8(vt + (df * 16 + c0) * 72 + ks2 * 32 + q4 * 8);
#pragma unroll
    for (int mf = 0; mf < 4; ++mf) {
      const int dyb = wid * 4 + mf - ct * 4 + 15;
      f32x4 sacc[4];
#pragma unroll
      for (int nf = 0; nf < 4; ++nf)
        sacc[nf] = *(const f32x4*)&tabh4[((dyb - nf) * 32 + dx0) * 4];
      __builtin_amdgcn_s_setprio(1);
#pragma unroll
      for (int nf = 0; nf < 4; ++nf)
        sacc[nf] = __builtin_amdgcn_mfma_f32_16x16x32_bf16(qa[mf], bfr[nf], sacc[nf], 0, 0, 0);
      __builtin_amdgcn_s_setprio(0);
#pragma unroll
      for (int nf = 0; nf < 4; ++nf) {
#pragma unroll
        for (int jj = 0; jj < 4; ++jj) {
          float p = EXP2(sacc[nf][jj]);
          psum[mf][jj] += p;
          pl[wid][(q4 * 4 + jj) * 76 + nf * 16 + c0] = cvt_bf(p);
        }
      }
      __builtin_amdgcn_s_setprio(1);
#pragma unroll
      for (int ks2 = 0; ks2 < 2; ++ks2) {
        bf16x8 pa = ld_bf8(&pl[wid][c0 * 76 + ks2 * 32 + q4 * 8]);
        oacc[mf][0] = __builtin_amdgcn_mfma_f32_16x16x32_bf16(pa, vfr[0][ks2], oacc[mf][0], 0, 0, 0);
        oacc[mf][1] = __builtin_amdgcn_mfma_f32_16x16x32_bf16(pa, vfr[1][ks2], oacc[mf][1], 0, 0, 0);
      }
      __builtin_amdgcn_s_setprio(0);
    }
    __syncthreads();
  }
#pragma unroll
  for (int mf = 0; mf < 4; ++mf) {
#pragma unroll
    for (int jj = 0; jj < 4; ++jj) {
      float s = psum[mf][jj];
      s += __shfl_xor(s, 1);
      s += __shfl_xor(s, 2);
      s += __shfl_xor(s, 4);
      s += __shfl_xor(s, 8);
      float inv = 1.f / s;
      int row = wid * 64 + mf * 16 + q4 * 4 + jj;
      size_t obase = ((size_t)w * 256 + row) * 512 + h * 32;
      ob[obase + c0] = f2bf(oacc[mf][0][jj] * inv);
      ob[obase + 16 + c0] = f2bf(oacc[mf][1][jj] * inv);
    }
  }
}

// ---------------- LN2 ----------------
__global__ __launch_bounds__(256, 4) void ln2_kernel(const u16* __restrict__ r1,
    const float* __restrict__ w, const float* __restrict__ b, u16* __restrict__ h2) {
  int t = threadIdx.x, l = t & 63, wid = t >> 6;
  size_t token = (size_t)blockIdx.x * 4 + wid;
  const u16* rp = r1 + token * 512 + l * 8;
  u16x8 raw = *(const u16x8*)rp;
  float v[8]; float s = 0.f, s2 = 0.f;
#pragma unroll
  for (int i = 0; i < 8; ++i) { v[i] = bf2f(raw[i]); s += v[i]; s2 += v[i] * v[i]; }
#pragma unroll
  for (int m = 1; m < 64; m <<= 1) { s += __shfl_xor(s, m); s2 += __shfl_xor(s2, m); }
  float mu = s * (1.f / 512.f);
  float var = s2 * (1.f / 512.f) - mu * mu;
  float rs = rsqrtf(var + 1e-5f);
  u16x8 o;
#pragma unroll
  for (int i = 0; i < 8; ++i) {
    int c = l * 8 + i;
    o[i] = f2bf((v[i] - mu) * rs * w[c] + b[c]);
  }
  *(u16x8*)(h2 + token * 512 + l * 8) = o;
}

extern "C" void kernel_launch(void* const* d_in, const int* in_sizes, int n_in,
                              void* d_out, int out_size, void* d_ws, size_t ws_size,
                              hipStream_t stream) {
  (void)in_sizes; (void)n_in; (void)out_size; (void)ws_size;
  const float* x = (const float*)d_in[0];
  const float* rel_table = (const float*)d_in[1];
  const float* n1w = (const float*)d_in[2];
  const float* n1b = (const float*)d_in[3];
  const float* n2w = (const float*)d_in[4];
  const float* n2b = (const float*)d_in[5];
  const float* qkv_w = (const float*)d_in[6];
  const float* proj_w = (const float*)d_in[7];
  const float* cpb_w1 = (const float*)d_in[8];
  const float* cpb_b1 = (const float*)d_in[9];
  const float* cpb_w2 = (const float*)d_in[10];
  const float* fc1_w = (const float*)d_in[11];
  const float* fc2_w = (const float*)d_in[12];
  float* outp = (float*)d_out;
  char* ws = (char*)d_ws;

  u16* wq = (u16*)(ws + 0);              // 1536x512 bf16 (q cols pre-scaled)
  u16* wp = (u16*)(ws + 1572864);        // 512x512
  u16* w1 = (u16*)(ws + 2097152);        // 2048x512 (permuted)
  u16* w2 = (u16*)(ws + 4194304);        // 512x1024
  float* tabh4g = (float*)(ws + 5242880);  // 16x992x4 f32 frag-replicated bias (254 KB)
  const size_t RB = 67108864;
  u16* R0 = (u16*)(ws + 8388608);            // xwbuf (proj residual)
  u16* R1 = (u16*)(ws + 8388608 + RB);       // r1
  u16* R2 = (u16*)(ws + 8388608 + 2 * RB);   // hbuf -> obuf
  u16* R3 = (u16*)(ws + 8388608 + 3 * RB);   // qkv (201MB, spans R3..R5) -> h2
  u16* R4 = (u16*)(ws + 8388608 + 4 * RB);   // gbuf (134MB, spans R4+R5)

  hipMemsetAsync(tabh4g, 0, (size_t)16 * 992 * 4 * sizeof(float), stream);
  head_kernel<<<13249, 256, 0, stream>>>(x, n1w, n1b, R2, R0,
                                         qkv_w, proj_w, fc1_w, fc2_w,
                                         rel_table, cpb_w1, cpb_b1, cpb_w2,
                                         wq, wp, w1, w2, tabh4g);
  gemm_bt<0><<<6144, 256, 0, stream>>>(R2, wq, R3, nullptr,
                                       nullptr, nullptr, 65536, 1536, 512);
  attn_kernel<<<dim3(16, 256), 256, 0, stream>>>(R3, tabh4g, R2);
  gemm_bt<1><<<2048, 256, 0, stream>>>(R2, wp, R1, R0,
                                       nullptr, nullptr, 65536, 512, 512);
  ln2_kernel<<<16384, 256, 0, stream>>>(R1, n2w, n2b, R3);
  gemm_bt<3><<<8192, 256, 0, stream>>>(R3, w1, R4, nullptr,
                                       nullptr, nullptr, 65536, 2048, 512);
  gemm_bt<4><<<2048, 256, 0, stream>>>(R4, w2, nullptr, R1,
                                       x, outp, 65536, 512, 1024);
}

// Round 15
// 714.284 us; speedup vs baseline: 1.1219x; 1.0104x over previous
//
#include <hip/hip_runtime.h>
#include <hip/hip_bf16.h>

typedef unsigned short u16;
typedef unsigned int u32;
typedef __attribute__((ext_vector_type(8))) u16 u16x8;
typedef __attribute__((ext_vector_type(4))) u16 u16x4;
typedef __attribute__((ext_vector_type(8))) short bf16x8;
typedef __attribute__((ext_vector_type(4))) float f32x4;

__device__ __forceinline__ u16 f2bf(float f) {
  u32 u = __float_as_uint(f);
  u += 0x7fffu + ((u >> 16) & 1u);
  return (u16)(u >> 16);
}
__device__ __forceinline__ float bf2f(u16 h) {
  return __uint_as_float(((u32)h) << 16);
}
__device__ __forceinline__ u16 cvt_bf(float f) {
  __hip_bfloat16 h(f);
  return __builtin_bit_cast(u16, h);
}
__device__ __forceinline__ bf16x8 ld_bf8(const u16* p) {
  return __builtin_bit_cast(bf16x8, *(const u16x8*)p);
}

#if __has_builtin(__builtin_amdgcn_exp2f)
#define EXP2(x) __builtin_amdgcn_exp2f(x)
#else
#define EXP2(x) exp2f(x)
#endif

typedef const void __attribute__((address_space(1)))* gas_t;
typedef void __attribute__((address_space(3)))* las_t;
#define GLOAD_LDS16(gp, lp) __builtin_amdgcn_global_load_lds((gas_t)(gp), (las_t)(lp), 16, 0, 0)

#define QSCALE 0.25503486f       // (1/sqrt(32)) * log2(e), folded into wq q-columns
#define BIAS_MUL 23.08312065f    // 16 * log2(e)

// ---------------- fused head: LN1 [0,2048) + weight prep + CPB-scatter [2048,13249) ----------------
__global__ __launch_bounds__(256, 4) void head_kernel(
    const float* __restrict__ x, const float* __restrict__ n1w, const float* __restrict__ n1b,
    u16* __restrict__ hbuf, u16* __restrict__ xwbuf,
    const float* __restrict__ qkv_w, const float* __restrict__ proj_w,
    const float* __restrict__ fc1_w, const float* __restrict__ fc2_w,
    const float* __restrict__ rt, const float* __restrict__ cw1,
    const float* __restrict__ cb1, const float* __restrict__ cw2,
    u16* __restrict__ wq, u16* __restrict__ wp, u16* __restrict__ w1,
    u16* __restrict__ w2, float* __restrict__ tabh4g) {
  __shared__ u16 tile[512 * 33];
  __shared__ float red[2][8][32];
  __shared__ float meanv[32], rstdv[32];
  int blk = blockIdx.x, t = threadIdx.x;
  if (blk < 2048) {
    // ---- LN1: 32 pixels per block (R8-proven) ----
    int bi = blk;
    int bimg = bi >> 7, rest = bi & 127, hrow = rest >> 1, half = rest & 1;
    int p = t & 31, g = t >> 5;
    const float* xr = x + (size_t)bimg * 512 * 4096 + (size_t)hrow * 64 + half * 32;
    float s = 0.f, s2 = 0.f;
    for (int i = 0; i < 64; ++i) {
      int c = g * 64 + i;
      float v = xr[(size_t)c * 4096 + p];
      tile[c * 33 + p] = f2bf(v);
      s += v; s2 += v * v;
    }
    red[0][g][p] = s; red[1][g][p] = s2;
    __syncthreads();
    if (t < 32) {
      float ss = 0.f, qq = 0.f;
      for (int gg = 0; gg < 8; ++gg) { ss += red[0][gg][t]; qq += red[1][gg][t]; }
      float mu = ss * (1.f / 512.f);
      float var = qq * (1.f / 512.f) - mu * mu;
      meanv[t] = mu;
      rstdv[t] = rsqrtf(var + 1e-5f);
    }
    __syncthreads();
    int c0 = t * 2;
    float w0 = n1w[c0], w1v = n1w[c0 + 1], b0 = n1b[c0], b1v = n1b[c0 + 1];
    int hy = hrow >> 4, iy = hrow & 15;
    for (int pp = 0; pp < 32; ++pp) {
      int pixel = half * 32 + pp;
      int wx = pixel >> 4, ix = pixel & 15;
      int widx = bimg * 16 + hy * 4 + wx;
      size_t basep = ((size_t)widx * 256 + iy * 16 + ix) * 512;
      u16 rb0 = tile[c0 * 33 + pp], rb1 = tile[(c0 + 1) * 33 + pp];
      float mu = meanv[pp], rs = rstdv[pp];
      float v0 = bf2f(rb0), v1 = bf2f(rb1);
      *(u32*)(xwbuf + basep + c0) = (u32)rb0 | ((u32)rb1 << 16);
      u16 h0 = f2bf((v0 - mu) * rs * w0 + b0);
      u16 h1 = f2bf((v1 - mu) * rs * w1v + b1v);
      *(u32*)(hbuf + basep + c0) = (u32)h0 | ((u32)h1 << 16);
    }
    return;
  }
  int b = blk - 2048;
  if (b < 3072) {
    int idx = b * 256 + t;  // qkv transpose, q cols pre-scaled
    int n = idx >> 9, k = idx & 511;
    float s = n < 512 ? QSCALE : 1.f;
    wq[idx] = f2bf(qkv_w[(size_t)k * 1536 + n] * s);
  } else if (b < 4096) {
    int idx = (b - 3072) * 256 + t;
    int n = idx >> 9, k = idx & 511;
    wp[idx] = f2bf(proj_w[(size_t)k * 512 + n]);
  } else if (b < 8192) {
    int idx = (b - 4096) * 256 + t;  // fc1 permuted
    int n = idx >> 9, k = idx & 511;
    int i = ((n >> 5) << 4) | (n & 15);
    int gsel = (n >> 4) & 1;
    w1[idx] = f2bf(fc1_w[(size_t)k * 2048 + i + gsel * 1024]);
  } else if (b < 10240) {
    int idx = (b - 8192) * 256 + t;  // fc2: N=512, K=1024
    int n = idx >> 10, k = idx & 1023;
    w2[idx] = f2bf(fc2_w[(size_t)k * 512 + n]);
  } else {
    // CPB MLP for one table entry tix; scatter per-head values into tabh4g
    float* hid = (float*)tile;                         // 512 f32
    float (*part)[17] = (float (*)[17])(tile + 4096);  // 16x17 f32
    int tix = b - 10240;  // 0..960
    float r0 = rt[tix * 2], r1 = rt[tix * 2 + 1];
    for (int j = t; j < 512; j += 256) {
      float v = r0 * cw1[j] + r1 * cw1[512 + j] + cb1[j];
      hid[j] = v > 0.f ? v : 0.f;
    }
    __syncthreads();
    int hh = t & 15, seg = t >> 4;
    float acc = 0.f;
    for (int j = seg * 32; j < seg * 32 + 32; ++j) acc += hid[j] * cw2[j * 16 + hh];
    part[seg][hh] = acc;
    __syncthreads();
    if (t < 16) {
      float s = 0.f;
      for (int g = 0; g < 16; ++g) s += part[g][t];
      float val = BIAS_MUL / (1.f + __expf(-s)) - 23.0f;
      int dy = tix / 31, c = tix - dy * 31;  // tix = dy*31 + c
#pragma unroll
      for (int r = 0; r < 4; ++r) {
        int dx = c - r;
        if (dx >= 0)
          tabh4g[((size_t)t * 992 + dy * 32 + dx) * 4 + r] = val;
      }
    }
  }
}

// ---------------- 128x128 bf16 MFMA GEMM + T2 seg-XOR swizzle, XCD-panel map ----------------
// EPI: 0 plain bf16 [row][N], 1 out = acc + res(bf16), 3 fused SwiGLU (permuted w1),
//      4 fused final: out_f32(CHW) = acc + res(bf16 tok) + res2(bf16 tok) — res2 = bf16(x)
template <int EPI>
__global__ __launch_bounds__(256, 4) void gemm_bt(
    const u16* __restrict__ A, const u16* __restrict__ Bt,
    u16* __restrict__ out, const u16* __restrict__ res,
    const u16* __restrict__ res2, float* __restrict__ outf,
    int M, int N, int K) {
  __shared__ u16 As[128 * 64];
  __shared__ u16 Bs[128 * 64];
  const int t = threadIdx.x, l = t & 63, wv = t >> 6;
  const int nbx = N >> 7;
  const int wg = (int)blockIdx.x;
  const int xcd = wg & 7, c = wg >> 3;
  const int cm = c / nbx;
  const int m0 = (xcd * 64 + cm) * 128, n0 = (c - cm * nbx) * 128;
  const int wr = wv >> 1, wc = wv & 1;
  const int lr = l & 15, lk = l >> 4;
  const int swz = lr & 7;
  f32x4 acc[4][4] = {};
  for (int kt = 0; kt < K; kt += 64) {
#pragma unroll
    for (int j = 0; j < 4; ++j) {
      int qi = j * 256 + t;
      int r = qi >> 3, s = qi & 7;
      int c8 = (s ^ (r & 7)) * 8;  // pre-swizzled source chunk
      GLOAD_LDS16(A + (size_t)(m0 + r) * K + kt + c8, As + (size_t)qi * 8);
    }
#pragma unroll
    for (int j = 0; j < 4; ++j) {
      int qi = j * 256 + t;
      int r = qi >> 3, s = qi & 7;
      int c8 = (s ^ (r & 7)) * 8;
      GLOAD_LDS16(Bt + (size_t)(n0 + r) * K + kt + c8, Bs + (size_t)qi * 8);
    }
    __syncthreads();
#pragma unroll
    for (int ks = 0; ks < 2; ++ks) {
      bf16x8 a[4], bb[4];
#pragma unroll
      for (int mf = 0; mf < 4; ++mf)
        a[mf] = ld_bf8(As + (wr * 64 + mf * 16 + lr) * 64 + (((ks * 4 + lk) ^ swz) << 3));
#pragma unroll
      for (int nf = 0; nf < 4; ++nf)
        bb[nf] = ld_bf8(Bs + (wc * 64 + nf * 16 + lr) * 64 + (((ks * 4 + lk) ^ swz) << 3));
#pragma unroll
      for (int mf = 0; mf < 4; ++mf)
#pragma unroll
        for (int nf = 0; nf < 4; ++nf)
          acc[mf][nf] = __builtin_amdgcn_mfma_f32_16x16x32_bf16(a[mf], bb[nf], acc[mf][nf], 0, 0, 0);
    }
    __syncthreads();
  }
#pragma unroll
  for (int mf = 0; mf < 4; ++mf) {
    int rbase = m0 + wr * 64 + mf * 16 + lk * 4;
    if constexpr (EPI == 3) {
#pragma unroll
      for (int nf = 0; nf < 4; nf += 2) {
        int colv = n0 + wc * 64 + nf * 16 + lr;
        int i = ((colv >> 5) << 4) | (colv & 15);
#pragma unroll
        for (int jj = 0; jj < 4; ++jj) {
          int row = rbase + jj;
          float val = acc[mf][nf][jj], gate = acc[mf][nf + 1][jj];
          float sil = gate / (1.f + __expf(-gate));
          out[(size_t)row * 1024 + i] = f2bf(sil * val);
        }
      }
    } else if constexpr (EPI == 4) {
      // token row -> (bimg, hy, wx, iy, ix); f32 CHW write, two bf16 token-major residuals
      int widx = rbase >> 8, iy = (rbase >> 4) & 15, ix0 = rbase & 15;
      int bimg = widx >> 4, hy = (widx >> 2) & 3, wx = widx & 3;
#pragma unroll
      for (int nf = 0; nf < 4; ++nf) {
        int col = n0 + wc * 64 + nf * 16 + lr;
        size_t obase = (((size_t)(bimg * 512 + col) * 64) + hy * 16 + iy) * 64 + wx * 16 + ix0;
        float* op = outf + obase;
#pragma unroll
        for (int jj = 0; jj < 4; ++jj) {
          size_t ti = (size_t)(rbase + jj) * 512 + col;
          op[jj] = acc[mf][nf][jj] + bf2f(res[ti]) + bf2f(res2[ti]);
        }
      }
    } else if constexpr (EPI == 1) {
#pragma unroll
      for (int nf = 0; nf < 4; ++nf) {
        int col = n0 + wc * 64 + nf * 16 + lr;
#pragma unroll
        for (int jj = 0; jj < 4; ++jj) {
          int row = rbase + jj;
          out[(size_t)row * N + col] = f2bf(acc[mf][nf][jj] + bf2f(res[(size_t)row * N + col]));
        }
      }
    } else {
#pragma unroll
      for (int nf = 0; nf < 4; ++nf) {
        int col = n0 + wc * 64 + nf * 16 + lr;
#pragma unroll
        for (int jj = 0; jj < 4; ++jj)
          out[(size_t)(rbase + jj) * N + col] = f2bf(acc[mf][nf][jj]);
      }
    }
  }
}

// ---------------- windowed flash attention (R10/R11 proven), precomputed bias table ----------------
__global__ __launch_bounds__(256, 4) void attn_kernel(
    const u16* __restrict__ qkv, const float* __restrict__ tabh4g, u16* __restrict__ ob) {
  __shared__ u16 vt[32 * 72];
  __shared__ float tabh4[31 * 32 * 4];
  __shared__ u16 pl[4][16 * 76];
  const int h = blockIdx.x, w = blockIdx.y;
  const int t = threadIdx.x, l = t & 63, wid = t >> 6;
  const u16* qg = qkv + (size_t)(w * 256) * 1536 + h * 32;
  const u16* kg = qg + 512;
  const u16* vg = qg + 1024;
  const float* tg = tabh4g + (size_t)h * 992 * 4;
  for (int i = t; i < 992; i += 256)
    *(f32x4*)&tabh4[i * 4] = *(const f32x4*)(tg + (size_t)i * 4);
  const int q4 = l >> 4, c0 = l & 15;
  const int dx0 = q4 * 4 - c0 + 15;
  bf16x8 qa[4];
#pragma unroll
  for (int mf = 0; mf < 4; ++mf)
    qa[mf] = ld_bf8(qg + (size_t)(wid * 64 + mf * 16 + c0) * 1536 + q4 * 8);
  f32x4 oacc[4][2] = {};
  float psum[4][4] = {};
  for (int ct = 0; ct < 4; ++ct) {
    {
      int r = t & 63, j = t >> 6;
      u16x8 dv = *(const u16x8*)(vg + (size_t)(ct * 64 + r) * 1536 + j * 8);
#pragma unroll
      for (int e = 0; e < 8; ++e) vt[(j * 8 + e) * 72 + r] = dv[e];
    }
    __syncthreads();
    bf16x8 bfr[4];
#pragma unroll
    for (int nf = 0; nf < 4; ++nf)
      bfr[nf] = ld_bf8(kg + (size_t)(ct * 64 + nf * 16 + c0) * 1536 + q4 * 8);
    bf16x8 vfr[2][2];
#pragma unroll
    for (int df = 0; df < 2; ++df)
#pragma unroll
      for (int ks2 = 0; ks2 < 2; ++ks2)
        vfr[df][ks2] = ld_bf8(vt + (df * 16 + c0) * 72 + ks2 * 32 + q4 * 8);
#pragma unroll
    for (int mf = 0; mf < 4; ++mf) {
      const int dyb = wid * 4 + mf - ct * 4 + 15;
      f32x4 sacc[4];
#pragma unroll
      for (int nf = 0; nf < 4; ++nf)
        sacc[nf] = *(const f32x4*)&tabh4[((dyb - nf) * 32 + dx0) * 4];
      __builtin_amdgcn_s_setprio(1);
#pragma unroll
      for (int nf = 0; nf < 4; ++nf)
        sacc[nf] = __builtin_amdgcn_mfma_f32_16x16x32_bf16(qa[mf], bfr[nf], sacc[nf], 0, 0, 0);
      __builtin_amdgcn_s_setprio(0);
#pragma unroll
      for (int nf = 0; nf < 4; ++nf) {
#pragma unroll
        for (int jj = 0; jj < 4; ++jj) {
          float p = EXP2(sacc[nf][jj]);
          psum[mf][jj] += p;
          pl[wid][(q4 * 4 + jj) * 76 + nf * 16 + c0] = cvt_bf(p);
        }
      }
      __builtin_amdgcn_s_setprio(1);
#pragma unroll
      for (int ks2 = 0; ks2 < 2; ++ks2) {
        bf16x8 pa = ld_bf8(&pl[wid][c0 * 76 + ks2 * 32 + q4 * 8]);
        oacc[mf][0] = __builtin_amdgcn_mfma_f32_16x16x32_bf16(pa, vfr[0][ks2], oacc[mf][0], 0, 0, 0);
        oacc[mf][1] = __builtin_amdgcn_mfma_f32_16x16x32_bf16(pa, vfr[1][ks2], oacc[mf][1], 0, 0, 0);
      }
      __builtin_amdgcn_s_setprio(0);
    }
    __syncthreads();
  }
#pragma unroll
  for (int mf = 0; mf < 4; ++mf) {
#pragma unroll
    for (int jj = 0; jj < 4; ++jj) {
      float s = psum[mf][jj];
      s += __shfl_xor(s, 1);
      s += __shfl_xor(s, 2);
      s += __shfl_xor(s, 4);
      s += __shfl_xor(s, 8);
      float inv = 1.f / s;
      int row = wid * 64 + mf * 16 + q4 * 4 + jj;
      size_t obase = ((size_t)w * 256 + row) * 512 + h * 32;
      ob[obase + c0] = f2bf(oacc[mf][0][jj] * inv);
      ob[obase + 16 + c0] = f2bf(oacc[mf][1][jj] * inv);
    }
  }
}

// ---------------- LN2 ----------------
__global__ __launch_bounds__(256, 4) void ln2_kernel(const u16* __restrict__ r1,
    const float* __restrict__ w, const float* __restrict__ b, u16* __restrict__ h2) {
  int t = threadIdx.x, l = t & 63, wid = t >> 6;
  size_t token = (size_t)blockIdx.x * 4 + wid;
  const u16* rp = r1 + token * 512 + l * 8;
  u16x8 raw = *(const u16x8*)rp;
  float v[8]; float s = 0.f, s2 = 0.f;
#pragma unroll
  for (int i = 0; i < 8; ++i) { v[i] = bf2f(raw[i]); s += v[i]; s2 += v[i] * v[i]; }
#pragma unroll
  for (int m = 1; m < 64; m <<= 1) { s += __shfl_xor(s, m); s2 += __shfl_xor(s2, m); }
  float mu = s * (1.f / 512.f);
  float var = s2 * (1.f / 512.f) - mu * mu;
  float rs = rsqrtf(var + 1e-5f);
  u16x8 o;
#pragma unroll
  for (int i = 0; i < 8; ++i) {
    int c = l * 8 + i;
    o[i] = f2bf((v[i] - mu) * rs * w[c] + b[c]);
  }
  *(u16x8*)(h2 + token * 512 + l * 8) = o;
}

extern "C" void kernel_launch(void* const* d_in, const int* in_sizes, int n_in,
                              void* d_out, int out_size, void* d_ws, size_t ws_size,
                              hipStream_t stream) {
  (void)in_sizes; (void)n_in; (void)out_size; (void)ws_size;
  const float* x = (const float*)d_in[0];
  const float* rel_table = (const float*)d_in[1];
  const float* n1w = (const float*)d_in[2];
  const float* n1b = (const float*)d_in[3];
  const float* n2w = (const float*)d_in[4];
  const float* n2b = (const float*)d_in[5];
  const float* qkv_w = (const float*)d_in[6];
  const float* proj_w = (const float*)d_in[7];
  const float* cpb_w1 = (const float*)d_in[8];
  const float* cpb_b1 = (const float*)d_in[9];
  const float* cpb_w2 = (const float*)d_in[10];
  const float* fc1_w = (const float*)d_in[11];
  const float* fc2_w = (const float*)d_in[12];
  float* outp = (float*)d_out;
  char* ws = (char*)d_ws;

  u16* wq = (u16*)(ws + 0);              // 1536x512 bf16 (q cols pre-scaled)
  u16* wp = (u16*)(ws + 1572864);        // 512x512
  u16* w1 = (u16*)(ws + 2097152);        // 2048x512 (permuted)
  u16* w2 = (u16*)(ws + 4194304);        // 512x1024
  float* tabh4g = (float*)(ws + 5242880);  // 16x992x4 f32 frag-replicated bias (254 KB)
  const size_t RB = 67108864;
  u16* R0 = (u16*)(ws + 8388608);            // xwbuf (bf16(x), token-major)
  u16* R1 = (u16*)(ws + 8388608 + RB);       // r1
  u16* R2 = (u16*)(ws + 8388608 + 2 * RB);   // hbuf -> obuf
  u16* R3 = (u16*)(ws + 8388608 + 3 * RB);   // qkv (201MB, spans R3..R5) -> h2
  u16* R4 = (u16*)(ws + 8388608 + 4 * RB);   // gbuf (134MB, spans R4+R5)

  hipMemsetAsync(tabh4g, 0, (size_t)16 * 992 * 4 * sizeof(float), stream);
  head_kernel<<<13249, 256, 0, stream>>>(x, n1w, n1b, R2, R0,
                                         qkv_w, proj_w, fc1_w, fc2_w,
                                         rel_table, cpb_w1, cpb_b1, cpb_w2,
                                         wq, wp, w1, w2, tabh4g);
  gemm_bt<0><<<6144, 256, 0, stream>>>(R2, wq, R3, nullptr,
                                       nullptr, nullptr, 65536, 1536, 512);
  attn_kernel<<<dim3(16, 256), 256, 0, stream>>>(R3, tabh4g, R2);
  gemm_bt<1><<<2048, 256, 0, stream>>>(R2, wp, R1, R0,
                                       nullptr, nullptr, 65536, 512, 512);
  ln2_kernel<<<16384, 256, 0, stream>>>(R1, n2w, n2b, R3);
  gemm_bt<3><<<8192, 256, 0, stream>>>(R3, w1, R4, nullptr,
                                       nullptr, nullptr, 65536, 2048, 512);
  gemm_bt<4><<<2048, 256, 0, stream>>>(R4, w2, nullptr, R1,
                                       R0, outp, 65536, 512, 1024);
}